// Round 6
// baseline (462.877 us; speedup 1.0000x reference)
//
#include <hip/hip_runtime.h>

// ---------------------------------------------------------------------------
// ResidualAttentionBlock: LN1 -> QKV -> MHA(12 heads, Dh=64) -> out+res ->
//                         LN2 -> FC(4E)+QuickGELU -> proj+res
// R6 == R5 with compile fix ('do' keyword param renamed).
// flash v4 — 2q x 2kv wave partition (frag LDS reads 40->24 b128/wave-tile,
//     K/V each read 2x not 4x), exp2 interleaved per-ni (S regs 64->16),
//     additive partial-O merged once in epilogue (max-free softmax),
//     3-barrier staging keeps async gl2lds covered. QKV GEMM TN=192
//     (grid 768 exact). Weight casts fused into one launch.
// ---------------------------------------------------------------------------

#define E 768
#define LSEQ 2048
#define PWS 40

typedef short bfrag __attribute__((ext_vector_type(8)));   // 8 bf16 = 4 VGPRs
typedef float facc  __attribute__((ext_vector_type(4)));   // 4 fp32 acc

__device__ __forceinline__ unsigned short f2bf(float f) {
  unsigned int u = __float_as_uint(f);
  u = (u + 0x7fffu + ((u >> 16) & 1u)) >> 16;   // RNE
  return (unsigned short)u;
}

__device__ __forceinline__ facc mfma16(bfrag a, bfrag b, facc c) {
  return __builtin_amdgcn_mfma_f32_16x16x32_bf16(a, b, c, 0, 0, 0);
}

__device__ __forceinline__ void gl2lds16(const void* g, void* l) {
  __builtin_amdgcn_global_load_lds((__attribute__((address_space(1))) void*)g,
                                   (__attribute__((address_space(3))) void*)l,
                                   16, 0, 0);
}

// --------------------------- fused fp32 -> bf16 weight cast ------------------
// blocks: [0,1728) w_qkv, [1728,2304) w_out, [2304,4608) w_fc, [4608,6912) w_proj
__global__ __launch_bounds__(256) void cvt_all_k(const float* __restrict__ wq,
                                                 const float* __restrict__ wo,
                                                 const float* __restrict__ wf,
                                                 const float* __restrict__ wp,
                                                 unsigned short* __restrict__ d0,
                                                 unsigned short* __restrict__ d1,
                                                 unsigned short* __restrict__ d2,
                                                 unsigned short* __restrict__ d3) {
  int b = blockIdx.x;
  const float* s; unsigned short* d; int off;
  if (b < 1728)      { s = wq; d = d0; off = b; }
  else if (b < 2304) { s = wo; d = d1; off = b - 1728; }
  else if (b < 4608) { s = wf; d = d2; off = b - 2304; }
  else               { s = wp; d = d3; off = b - 4608; }
  int i = (off * 256 + threadIdx.x) * 4;
  float4 v = *(const float4*)(s + i);
  uint2 u;
  u.x = (unsigned)f2bf(v.x) | ((unsigned)f2bf(v.y) << 16);
  u.y = (unsigned)f2bf(v.z) | ((unsigned)f2bf(v.w) << 16);
  *(uint2*)(d + i) = u;
}

// --------------------------- LayerNorm (fp32 in, bf16 out) ------------------
__global__ __launch_bounds__(256) void ln_bf16_k(const float* __restrict__ x,
                                                 const float* __restrict__ w,
                                                 const float* __restrict__ b,
                                                 unsigned short* __restrict__ out) {
  int row = blockIdx.x * 4 + (threadIdx.x >> 6);
  int lane = threadIdx.x & 63;
  const float* xr = x + row * E;
  float4 v[3];
  float s = 0.f, ss = 0.f;
#pragma unroll
  for (int i = 0; i < 3; ++i) {
    v[i] = *(const float4*)(xr + i * 256 + lane * 4);
    s += v[i].x + v[i].y + v[i].z + v[i].w;
    ss += v[i].x * v[i].x + v[i].y * v[i].y + v[i].z * v[i].z + v[i].w * v[i].w;
  }
#pragma unroll
  for (int m = 32; m; m >>= 1) { s += __shfl_xor(s, m); ss += __shfl_xor(ss, m); }
  float mu = s * (1.f / E);
  float rstd = rsqrtf(ss * (1.f / E) - mu * mu + 1e-5f);
#pragma unroll
  for (int i = 0; i < 3; ++i) {
    int c = i * 256 + lane * 4;
    float4 wv = *(const float4*)(w + c);
    float4 bv = *(const float4*)(b + c);
    float y0 = (v[i].x - mu) * rstd * wv.x + bv.x;
    float y1 = (v[i].y - mu) * rstd * wv.y + bv.y;
    float y2 = (v[i].z - mu) * rstd * wv.z + bv.z;
    float y3 = (v[i].w - mu) * rstd * wv.w + bv.w;
    uint2 o;
    o.x = (unsigned)f2bf(y0) | ((unsigned)f2bf(y1) << 16);
    o.y = (unsigned)f2bf(y2) | ((unsigned)f2bf(y3) << 16);
    *(uint2*)(out + row * E + c) = o;
  }
}

// --------------------------- GEMM: C[M,N] = A[M,K] * W[N,K]^T + epilogue ----
// TM=128 always; TN in {64,128,192}. 4 waves as 2x2 (wn covers TN/2).
template <int MODE, int TN>
__global__ __launch_bounds__(256) void gemm_bt(const unsigned short* __restrict__ A,
                                               const unsigned short* __restrict__ Bw,
                                               const float* __restrict__ bias,
                                               const float* __restrict__ resid,
                                               void* __restrict__ Cout, int K, int N) {
  __shared__ unsigned short Al[128 * 32];
  __shared__ unsigned short Bl[TN * 32];
  constexpr int NI = TN / 32;
  constexpr int BCH = TN * 32 / 8 / 256;   // B 16B-chunks per thread
  int tid = threadIdx.x;
  int lane = tid & 63, w = tid >> 6;
  int q4 = lane >> 4, m16 = lane & 15;
  int m0 = blockIdx.x * 128, n0 = blockIdx.y * TN;
  int wm = (w >> 1) * 64, wn = (w & 1) * (TN / 2);
  facc zf = {0.f, 0.f, 0.f, 0.f};
  facc acc[4][NI];
#pragma unroll
  for (int mi = 0; mi < 4; ++mi)
#pragma unroll
    for (int ni = 0; ni < NI; ++ni) acc[mi][ni] = zf;

  for (int k0 = 0; k0 < K; k0 += 32) {
#pragma unroll
    for (int i = 0; i < 2; ++i) {
      int c = i * 256 + tid;
      gl2lds16(A + (m0 + (c >> 2)) * K + k0 + (c & 3) * 8, &Al[c * 8]);
    }
#pragma unroll
    for (int i = 0; i < BCH; ++i) {
      int c = i * 256 + tid;
      gl2lds16(Bw + (n0 + (c >> 2)) * K + k0 + (c & 3) * 8, &Bl[c * 8]);
    }
    __syncthreads();
    bfrag a[4], bb[NI];
#pragma unroll
    for (int mi = 0; mi < 4; ++mi)
      a[mi] = *(const bfrag*)&Al[(wm + mi * 16 + m16) * 32 + q4 * 8];
#pragma unroll
    for (int ni = 0; ni < NI; ++ni)
      bb[ni] = *(const bfrag*)&Bl[(wn + ni * 16 + m16) * 32 + q4 * 8];
#pragma unroll
    for (int mi = 0; mi < 4; ++mi)
#pragma unroll
      for (int ni = 0; ni < NI; ++ni)
        acc[mi][ni] = mfma16(a[mi], bb[ni], acc[mi][ni]);
    __syncthreads();
  }

#pragma unroll
  for (int mi = 0; mi < 4; ++mi)
#pragma unroll
    for (int ni = 0; ni < NI; ++ni)
#pragma unroll
      for (int r = 0; r < 4; ++r) {
        int row = m0 + wm + mi * 16 + q4 * 4 + r;
        int col = n0 + wn + ni * 16 + m16;
        float vv = acc[mi][ni][r] + bias[col];
        if constexpr (MODE == 1) {
          ((float*)Cout)[row * N + col] = vv + resid[row * N + col];
        } else if constexpr (MODE == 2) {
          float g = vv / (1.f + __expf(-1.702f * vv));
          ((unsigned short*)Cout)[row * N + col] = f2bf(g);
        } else {
          ((unsigned short*)Cout)[row * N + col] = f2bf(vv);
        }
      }
}

// --------------------------- V transpose ------------------------------------
__global__ __launch_bounds__(256) void vtrans_k(const unsigned short* __restrict__ qkv,
                                                unsigned short* __restrict__ vt) {
  __shared__ unsigned short T[64 * 72];
  int tid = threadIdx.x;
  int l0 = blockIdx.x * 64;
  int by = blockIdx.y;
  int n = by & 3, h = by >> 2;
#pragma unroll
  for (int i = 0; i < 2; ++i) {
    int u = i * 256 + tid;
    int r = u >> 3, c8 = u & 7;
    uint4 v4 = *(const uint4*)(qkv + ((l0 + r) * 4 + n) * 2304 + 1536 + h * 64 + c8 * 8);
    *(uint4*)&T[r * 72 + c8 * 8] = v4;
  }
  __syncthreads();
#pragma unroll
  for (int i = 0; i < 2; ++i) {
    int u = i * 256 + tid;
    int d = u >> 3, c8 = u & 7;
    unsigned short e[8];
#pragma unroll
    for (int jj = 0; jj < 8; ++jj) {
      int j = jj ^ (c8 & 7);
      e[j] = T[(c8 * 8 + j) * 72 + d];
    }
    uint4 o4;
    o4.x = (unsigned)e[0] | ((unsigned)e[1] << 16);
    o4.y = (unsigned)e[2] | ((unsigned)e[3] << 16);
    o4.z = (unsigned)e[4] | ((unsigned)e[5] << 16);
    o4.w = (unsigned)e[6] | ((unsigned)e[7] << 16);
    *(uint4*)(vt + ((size_t)by * 64 + d) * 2048 + l0 + c8 * 8) = o4;
  }
}

// --------------------------- Flash attention (v4) ----------------------------
// grid (16, 48); 4 waves = 2 q-groups x 2 kv-groups. Wave (qg,kg) computes
// S-quadrant [qg*64..+64][kg*64..+64] and partial O over its kv-half; partials
// are additive (max-free softmax) and merged once in the epilogue via LDS.
// Kl [128][64], Vtl [64][128], both XOR-chunk-swizzled, gl2lds-staged with
// 3 barriers/tile so every restage is covered by >=1 compute phase.
__global__ __launch_bounds__(256) void flash_k(const unsigned short* __restrict__ qkv,
                                               const unsigned short* __restrict__ vt,
                                               unsigned short* __restrict__ o) {
  __shared__ __align__(16) char smemc[53248];
  unsigned short* Kl  = (unsigned short*)smemc;             // [128][64] 16KB
  unsigned short* Vtl = (unsigned short*)(smemc + 16384);   // [64][128] 16KB
  unsigned short* Pp  = (unsigned short*)(smemc + 32768);   // [4][64][PWS] 20KB
  int tid = threadIdx.x;
  int lane = tid & 63, w = tid >> 6;
  int qg = w >> 1, kg = w & 1;
  int q4 = lane >> 4, m16 = lane & 15;
  int qt = blockIdx.x, by = blockIdx.y;
  int n = by & 3, h = by >> 2;
  const unsigned short* vtb = vt + (size_t)by * 64 * 2048;
  int wpb = w * 64 * PWS;
  int ksw = m16 & 7;

  // Q fragments: 64 q-rows per wave
  bfrag qf[4][2];
#pragma unroll
  for (int mi = 0; mi < 4; ++mi) {
    int l = qt * 128 + qg * 64 + mi * 16 + m16;
#pragma unroll
    for (int ki = 0; ki < 2; ++ki)
      qf[mi][ki] = *(const bfrag*)(qkv + (size_t)(l * 4 + n) * 2304 + h * 64 + ki * 32 + q4 * 8);
  }

  facc zf = {0.f, 0.f, 0.f, 0.f};
  facc accO[4][4];
  float lrow[4][4];
#pragma unroll
  for (int mi = 0; mi < 4; ++mi)
#pragma unroll
    for (int j = 0; j < 4; ++j) { accO[mi][j] = zf; lrow[mi][j] = 0.f; }

  const float cs = 0.125f * 1.44269504088896f;

  // tile 0 full stage
#pragma unroll
  for (int i = 0; i < 4; ++i) {
    int F = i * 256 + tid;
    int r = F >> 3, cd = F & 7, csr = cd ^ (r & 7);
    gl2lds16(qkv + (size_t)(r * 4 + n) * 2304 + 768 + h * 64 + csr * 8, &Kl[F * 8]);
    int d = F >> 4, cdv = F & 15, cv = cdv ^ (d & 7);
    gl2lds16(vtb + d * 2048 + cv * 8, &Vtl[F * 8]);
  }
  __syncthreads();

  for (int kt = 0; kt < 16; ++kt) {
    int kvn = (kt + 1) * 128;
    // ---- phase A: QK ni=0,1 (+exp, P cols 0..31) ----
#pragma unroll
    for (int ni = 0; ni < 2; ++ni) {
      facc S[4] = {zf, zf, zf, zf};
#pragma unroll
      for (int ki = 0; ki < 2; ++ki) {
        bfrag bk = *(const bfrag*)&Kl[(kg * 64 + ni * 16 + m16) * 64 + (((ki * 4 + q4) ^ ksw) << 3)];
#pragma unroll
        for (int mi = 0; mi < 4; ++mi) S[mi] = mfma16(qf[mi][ki], bk, S[mi]);
      }
#pragma unroll
      for (int mi = 0; mi < 4; ++mi)
#pragma unroll
        for (int r = 0; r < 4; ++r) {
          float p = __builtin_amdgcn_exp2f(S[mi][r] * cs);
          lrow[mi][r] += p;
          Pp[wpb + (mi * 16 + q4 * 4 + r) * PWS + ni * 16 + m16] = (unsigned short)(__float_as_uint(p) >> 16);
        }
    }
    // ---- phase B: PV slice 0 (kv chunks kg*8 + 0..3) ----
    {
      bfrag pa[4];
#pragma unroll
      for (int mi = 0; mi < 4; ++mi)
        pa[mi] = *(const bfrag*)&Pp[wpb + (mi * 16 + m16) * PWS + q4 * 8];
#pragma unroll
      for (int di = 0; di < 4; ++di) {
        bfrag bv = *(const bfrag*)&Vtl[(di * 16 + m16) * 128 + (((kg * 8 + q4) ^ ksw) << 3)];
#pragma unroll
        for (int mi = 0; mi < 4; ++mi) accO[mi][di] = mfma16(pa[mi], bv, accO[mi][di]);
      }
    }
    __syncthreads();                     // bar1: V slice0 reads done
    if (kt < 15) {
#pragma unroll
      for (int i = 0; i < 2; ++i) {      // restage V slice0 (dest chunks 0..7)
        int F = i * 256 + tid;
        int d = F >> 3, cd = F & 7, cv = cd ^ (d & 7);
        gl2lds16(vtb + d * 2048 + kvn + cv * 8, &Vtl[d * 128 + cd * 8]);
      }
    }
    // ---- phase C: QK ni=2,3 (+exp, P cols 0..31 reused) ----
#pragma unroll
    for (int ni = 2; ni < 4; ++ni) {
      facc S[4] = {zf, zf, zf, zf};
#pragma unroll
      for (int ki = 0; ki < 2; ++ki) {
        bfrag bk = *(const bfrag*)&Kl[(kg * 64 + ni * 16 + m16) * 64 + (((ki * 4 + q4) ^ ksw) << 3)];
#pragma unroll
        for (int mi = 0; mi < 4; ++mi) S[mi] = mfma16(qf[mi][ki], bk, S[mi]);
      }
#pragma unroll
      for (int mi = 0; mi < 4; ++mi)
#pragma unroll
        for (int r = 0; r < 4; ++r) {
          float p = __builtin_amdgcn_exp2f(S[mi][r] * cs);
          lrow[mi][r] += p;
          Pp[wpb + (mi * 16 + q4 * 4 + r) * PWS + (ni - 2) * 16 + m16] = (unsigned short)(__float_as_uint(p) >> 16);
        }
    }
    __syncthreads();                     // bar2: K reads done (also drains V0)
    if (kt < 15) {
#pragma unroll
      for (int i = 0; i < 4; ++i) {      // restage K
        int F = i * 256 + tid;
        int r = F >> 3, cd = F & 7, csr = cd ^ (r & 7);
        gl2lds16(qkv + (size_t)((kvn + r) * 4 + n) * 2304 + 768 + h * 64 + csr * 8, &Kl[F * 8]);
      }
    }
    // ---- phase D: PV slice 1 (kv chunks kg*8 + 4..7) ----
    {
      bfrag pa[4];
#pragma unroll
      for (int mi = 0; mi < 4; ++mi)
        pa[mi] = *(const bfrag*)&Pp[wpb + (mi * 16 + m16) * PWS + q4 * 8];
#pragma unroll
      for (int di = 0; di < 4; ++di) {
        bfrag bv = *(const bfrag*)&Vtl[(di * 16 + m16) * 128 + (((kg * 8 + 4 + q4) ^ ksw) << 3)];
#pragma unroll
        for (int mi = 0; mi < 4; ++mi) accO[mi][di] = mfma16(pa[mi], bv, accO[mi][di]);
      }
    }
    __syncthreads();                     // bar3: V slice1 reads done (drains K)
    if (kt < 15) {
#pragma unroll
      for (int i = 0; i < 2; ++i) {      // restage V slice1 (dest chunks 8..15)
        int F = i * 256 + tid;
        int d = F >> 3, cd = 8 + (F & 7), cv = cd ^ (d & 7);
        gl2lds16(vtb + d * 2048 + kvn + cv * 8, &Vtl[d * 128 + cd * 8]);
      }
    }
  }

  // ---- epilogue: merge kv-halves, normalize, store ----
  float hl[4][4];
#pragma unroll
  for (int mi = 0; mi < 4; ++mi)
#pragma unroll
    for (int r = 0; r < 4; ++r) {
      float ls = lrow[mi][r];
      ls += __shfl_xor(ls, 1);
      ls += __shfl_xor(ls, 2);
      ls += __shfl_xor(ls, 4);
      ls += __shfl_xor(ls, 8);
      hl[mi][r] = ls;
    }
  float* mrg  = (float*)smemc;            // 8192 floats over Kl+Vtl
  float* lscr = (float*)(smemc + 32768);  // 128 floats in Pp region
  if (kg == 1) {
#pragma unroll
    for (int mi = 0; mi < 4; ++mi)
#pragma unroll
      for (int r = 0; r < 4; ++r) {
        int row = mi * 16 + q4 * 4 + r;
#pragma unroll
        for (int di = 0; di < 4; ++di)
          mrg[qg * 4096 + row * 64 + di * 16 + m16] = accO[mi][di][r];
        lscr[qg * 64 + row] = hl[mi][r];
      }
  }
  __syncthreads();
  if (kg == 0) {
#pragma unroll
    for (int mi = 0; mi < 4; ++mi)
#pragma unroll
      for (int r = 0; r < 4; ++r) {
        int row = mi * 16 + q4 * 4 + r;
        float inv = 1.f / (hl[mi][r] + lscr[qg * 64 + row]);
        int l = qt * 128 + qg * 64 + row;
#pragma unroll
        for (int di = 0; di < 4; ++di) {
          float v = accO[mi][di][r] + mrg[qg * 4096 + row * 64 + di * 16 + m16];
          o[(size_t)(l * 4 + n) * 768 + h * 64 + di * 16 + m16] = f2bf(v * inv);
        }
      }
  }
}

// --------------------------- launcher ---------------------------------------
extern "C" void kernel_launch(void* const* d_in, const int* in_sizes, int n_in,
                              void* d_out, int out_size, void* d_ws, size_t ws_size,
                              hipStream_t stream) {
  (void)in_sizes; (void)n_in; (void)out_size; (void)ws_size;
  const float* x      = (const float*)d_in[0];
  const float* ln1_w  = (const float*)d_in[1];
  const float* ln1_b  = (const float*)d_in[2];
  const float* w_qkv  = (const float*)d_in[3];
  const float* b_qkv  = (const float*)d_in[4];
  const float* w_out  = (const float*)d_in[5];
  const float* b_out  = (const float*)d_in[6];
  const float* ln2_w  = (const float*)d_in[7];
  const float* ln2_b  = (const float*)d_in[8];
  const float* w_fc   = (const float*)d_in[9];
  const float* b_fc   = (const float*)d_in[10];
  const float* w_proj = (const float*)d_in[11];
  const float* b_proj = (const float*)d_in[12];

  char* ws = (char*)d_ws;
  unsigned short* qkv_bf  = (unsigned short*)(ws);
  unsigned short* o_bf    = (unsigned short*)(ws + 37748736);
  unsigned short* f_bf    = (unsigned short*)(ws);
  unsigned short* h_bf    = (unsigned short*)(ws + 50331648);
  float*          x1      = (float*)        (ws + 62914560);
  unsigned short* vt      = (unsigned short*)(ws + 62914560);  // dead before x1 written
  unsigned short* wqkv_bf = (unsigned short*)(ws + 88080384);
  unsigned short* wout_bf = (unsigned short*)(ws + 91619328);
  unsigned short* wfc_bf  = (unsigned short*)(ws + 92798976);
  unsigned short* wproj_bf= (unsigned short*)(ws + 97517568);

  cvt_all_k<<<6912, 256, 0, stream>>>(w_qkv, w_out, w_fc, w_proj,
                                      wqkv_bf, wout_bf, wfc_bf, wproj_bf);

  ln_bf16_k<<<2048, 256, 0, stream>>>(x, ln1_w, ln1_b, h_bf);
  gemm_bt<0, 192><<<dim3(64, 12), 256, 0, stream>>>(h_bf, wqkv_bf, b_qkv, nullptr, qkv_bf, 768, 2304);
  vtrans_k<<<dim3(32, 48), 256, 0, stream>>>(qkv_bf, vt);
  flash_k<<<dim3(16, 48), 256, 0, stream>>>(qkv_bf, vt, o_bf);
  gemm_bt<1, 64><<<dim3(64, 12), 256, 0, stream>>>(o_bf, wout_bf, b_out, x, x1, 768, 768);
  ln_bf16_k<<<2048, 256, 0, stream>>>(x1, ln2_w, ln2_b, h_bf);
  gemm_bt<2, 128><<<dim3(64, 24), 256, 0, stream>>>(h_bf, wfc_bf, b_fc, nullptr, f_bf, 768, 3072);
  gemm_bt<1, 64><<<dim3(64, 12), 256, 0, stream>>>(f_bf, wproj_bf, b_proj, x1, (float*)d_out, 3072, 768);
}

// Round 7
// 430.697 us; speedup vs baseline: 1.0747x; 1.0747x over previous
//
#include <hip/hip_runtime.h>

// ---------------------------------------------------------------------------
// ResidualAttentionBlock: LN1 -> QKV -> MHA(12 heads, Dh=64) -> out+res ->
//                         LN2 -> FC(4E)+QuickGELU -> proj+res
// R7: flash reverted to R4's kernel (127.6us measured; R5/R6 kv-split
//     regressed). GEMMs: BK=64 (half the barrier drains at K=768/3072),
//     XOR-chunk-swizzled LDS staging (bank-safe wide rows, dest stays
//     lane-contiguous for gl2lds). Keep R6 wins: TN=192 QKV (grid 768
//     exact), fused weight cast.
// ---------------------------------------------------------------------------

#define E 768
#define LSEQ 2048
#define PW 40

typedef short bfrag __attribute__((ext_vector_type(8)));   // 8 bf16 = 4 VGPRs
typedef float facc  __attribute__((ext_vector_type(4)));   // 4 fp32 acc

__device__ __forceinline__ unsigned short f2bf(float f) {
  unsigned int u = __float_as_uint(f);
  u = (u + 0x7fffu + ((u >> 16) & 1u)) >> 16;   // RNE
  return (unsigned short)u;
}

__device__ __forceinline__ facc mfma16(bfrag a, bfrag b, facc c) {
  return __builtin_amdgcn_mfma_f32_16x16x32_bf16(a, b, c, 0, 0, 0);
}

__device__ __forceinline__ void gl2lds16(const void* g, void* l) {
  __builtin_amdgcn_global_load_lds((__attribute__((address_space(1))) void*)g,
                                   (__attribute__((address_space(3))) void*)l,
                                   16, 0, 0);
}

// --------------------------- fused fp32 -> bf16 weight cast ------------------
// blocks: [0,1728) w_qkv, [1728,2304) w_out, [2304,4608) w_fc, [4608,6912) w_proj
__global__ __launch_bounds__(256) void cvt_all_k(const float* __restrict__ wq,
                                                 const float* __restrict__ wo,
                                                 const float* __restrict__ wf,
                                                 const float* __restrict__ wp,
                                                 unsigned short* __restrict__ d0,
                                                 unsigned short* __restrict__ d1,
                                                 unsigned short* __restrict__ d2,
                                                 unsigned short* __restrict__ d3) {
  int b = blockIdx.x;
  const float* s; unsigned short* d; int off;
  if (b < 1728)      { s = wq; d = d0; off = b; }
  else if (b < 2304) { s = wo; d = d1; off = b - 1728; }
  else if (b < 4608) { s = wf; d = d2; off = b - 2304; }
  else               { s = wp; d = d3; off = b - 4608; }
  int i = (off * 256 + threadIdx.x) * 4;
  float4 v = *(const float4*)(s + i);
  uint2 u;
  u.x = (unsigned)f2bf(v.x) | ((unsigned)f2bf(v.y) << 16);
  u.y = (unsigned)f2bf(v.z) | ((unsigned)f2bf(v.w) << 16);
  *(uint2*)(d + i) = u;
}

// --------------------------- LayerNorm (fp32 in, bf16 out) ------------------
__global__ __launch_bounds__(256) void ln_bf16_k(const float* __restrict__ x,
                                                 const float* __restrict__ w,
                                                 const float* __restrict__ b,
                                                 unsigned short* __restrict__ out) {
  int row = blockIdx.x * 4 + (threadIdx.x >> 6);
  int lane = threadIdx.x & 63;
  const float* xr = x + row * E;
  float4 v[3];
  float s = 0.f, ss = 0.f;
#pragma unroll
  for (int i = 0; i < 3; ++i) {
    v[i] = *(const float4*)(xr + i * 256 + lane * 4);
    s += v[i].x + v[i].y + v[i].z + v[i].w;
    ss += v[i].x * v[i].x + v[i].y * v[i].y + v[i].z * v[i].z + v[i].w * v[i].w;
  }
#pragma unroll
  for (int m = 32; m; m >>= 1) { s += __shfl_xor(s, m); ss += __shfl_xor(ss, m); }
  float mu = s * (1.f / E);
  float rstd = rsqrtf(ss * (1.f / E) - mu * mu + 1e-5f);
#pragma unroll
  for (int i = 0; i < 3; ++i) {
    int c = i * 256 + lane * 4;
    float4 wv = *(const float4*)(w + c);
    float4 bv = *(const float4*)(b + c);
    float y0 = (v[i].x - mu) * rstd * wv.x + bv.x;
    float y1 = (v[i].y - mu) * rstd * wv.y + bv.y;
    float y2 = (v[i].z - mu) * rstd * wv.z + bv.z;
    float y3 = (v[i].w - mu) * rstd * wv.w + bv.w;
    uint2 o;
    o.x = (unsigned)f2bf(y0) | ((unsigned)f2bf(y1) << 16);
    o.y = (unsigned)f2bf(y2) | ((unsigned)f2bf(y3) << 16);
    *(uint2*)(out + row * E + c) = o;
  }
}

// --------------------------- GEMM: C[M,N] = A[M,K] * W[N,K]^T + epilogue ----
// TM=128, BK=64 (half the barrier drains vs BK=32; LDS <= 40KB keeps
// 3 blocks/CU). LDS rows XOR-chunk-swizzled: chunk j of row r holds source
// chunk j^(r&7); fragment reads then spread all 32 banks (2 lanes/bank).
template <int MODE, int TN>
__global__ __launch_bounds__(256) void gemm_bt(const unsigned short* __restrict__ A,
                                               const unsigned short* __restrict__ Bw,
                                               const float* __restrict__ bias,
                                               const float* __restrict__ resid,
                                               void* __restrict__ Cout, int K, int N) {
  __shared__ unsigned short Al[128 * 64];
  __shared__ unsigned short Bl[TN * 64];
  constexpr int NI = TN / 32;
  int tid = threadIdx.x;
  int lane = tid & 63, w = tid >> 6;
  int q4 = lane >> 4, m16 = lane & 15;
  int m0 = blockIdx.x * 128, n0 = blockIdx.y * TN;
  int wm = (w >> 1) * 64, wn = (w & 1) * (TN / 2);
  facc zf = {0.f, 0.f, 0.f, 0.f};
  facc acc[4][NI];
#pragma unroll
  for (int mi = 0; mi < 4; ++mi)
#pragma unroll
    for (int ni = 0; ni < NI; ++ni) acc[mi][ni] = zf;

  for (int k0 = 0; k0 < K; k0 += 64) {
#pragma unroll
    for (int i = 0; i < 4; ++i) {            // A: 128 rows x 8 chunks
      int F = i * 256 + tid;
      int r = F >> 3, j = F & 7, js = j ^ (r & 7);
      gl2lds16(A + (m0 + r) * K + k0 + js * 8, &Al[F * 8]);
    }
#pragma unroll
    for (int i = 0; i < TN / 32; ++i) {      // B: TN rows x 8 chunks
      int F = i * 256 + tid;
      int r = F >> 3, j = F & 7, js = j ^ (r & 7);
      gl2lds16(Bw + (n0 + r) * K + k0 + js * 8, &Bl[F * 8]);
    }
    __syncthreads();
#pragma unroll
    for (int ks = 0; ks < 2; ++ks) {
      bfrag a[4], bb[NI];
#pragma unroll
      for (int mi = 0; mi < 4; ++mi) {
        int row = wm + mi * 16 + m16;
        a[mi] = *(const bfrag*)&Al[row * 64 + (((ks * 4 + q4) ^ (row & 7)) << 3)];
      }
#pragma unroll
      for (int ni = 0; ni < NI; ++ni) {
        int row = wn + ni * 16 + m16;
        bb[ni] = *(const bfrag*)&Bl[row * 64 + (((ks * 4 + q4) ^ (row & 7)) << 3)];
      }
#pragma unroll
      for (int mi = 0; mi < 4; ++mi)
#pragma unroll
        for (int ni = 0; ni < NI; ++ni)
          acc[mi][ni] = mfma16(a[mi], bb[ni], acc[mi][ni]);
    }
    __syncthreads();
  }

#pragma unroll
  for (int mi = 0; mi < 4; ++mi)
#pragma unroll
    for (int ni = 0; ni < NI; ++ni)
#pragma unroll
      for (int r = 0; r < 4; ++r) {
        int row = m0 + wm + mi * 16 + q4 * 4 + r;
        int col = n0 + wn + ni * 16 + m16;
        float vv = acc[mi][ni][r] + bias[col];
        if constexpr (MODE == 1) {
          ((float*)Cout)[row * N + col] = vv + resid[row * N + col];
        } else if constexpr (MODE == 2) {
          float g = vv / (1.f + __expf(-1.702f * vv));
          ((unsigned short*)Cout)[row * N + col] = f2bf(g);
        } else {
          ((unsigned short*)Cout)[row * N + col] = f2bf(vv);
        }
      }
}

// --------------------------- V transpose ------------------------------------
// qkv V-block [l,n][h*64+d] -> vt[by][d][l], by = h*4+n
__global__ __launch_bounds__(256) void vtrans_k(const unsigned short* __restrict__ qkv,
                                                unsigned short* __restrict__ vt) {
  __shared__ unsigned short T[64 * 72];
  int tid = threadIdx.x;
  int l0 = blockIdx.x * 64;
  int by = blockIdx.y;
  int n = by & 3, h = by >> 2;
#pragma unroll
  for (int i = 0; i < 2; ++i) {
    int u = i * 256 + tid;
    int r = u >> 3, c8 = u & 7;
    uint4 v4 = *(const uint4*)(qkv + ((l0 + r) * 4 + n) * 2304 + 1536 + h * 64 + c8 * 8);
    *(uint4*)&T[r * 72 + c8 * 8] = v4;
  }
  __syncthreads();
#pragma unroll
  for (int i = 0; i < 2; ++i) {
    int u = i * 256 + tid;
    int d = u >> 3, c8 = u & 7;
    unsigned short e[8];
#pragma unroll
    for (int jj = 0; jj < 8; ++jj) {
      int j = jj ^ (c8 & 7);
      e[j] = T[(c8 * 8 + j) * 72 + d];
    }
    uint4 o4;
    o4.x = (unsigned)e[0] | ((unsigned)e[1] << 16);
    o4.y = (unsigned)e[2] | ((unsigned)e[3] << 16);
    o4.z = (unsigned)e[4] | ((unsigned)e[5] << 16);
    o4.w = (unsigned)e[6] | ((unsigned)e[7] << 16);
    *(uint4*)(vt + ((size_t)by * 64 + d) * 2048 + l0 + c8 * 8) = o4;
  }
}

// --------------------------- Flash attention (R4 kernel, verbatim) ----------
// grid (16 q-tiles of 128, 48 by=(h*4+n)); 4 waves, 32 q-rows each.
// Kl [kv][64] / Vtl [d][128] XOR-chunk-swizzled, async gl2lds staged:
// K(t+1) issued mid-tile, V(t+1) at tile end. P: per-wave private scratch.
__global__ __launch_bounds__(256) void flash_k(const unsigned short* __restrict__ qkv,
                                               const unsigned short* __restrict__ vt,
                                               unsigned short* __restrict__ o) {
  __shared__ unsigned short Kl[128 * 64];    // 16 KB
  __shared__ unsigned short Vtl[64 * 128];   // 16 KB
  __shared__ unsigned short Pp[4 * 32 * PW]; // 10 KB
  int tid = threadIdx.x;
  int lane = tid & 63, w = tid >> 6;
  int q4 = lane >> 4, m16 = lane & 15;
  int qt = blockIdx.x;
  int by = blockIdx.y;
  int n = by & 3, h = by >> 2;
  const unsigned short* vtb = vt + (size_t)by * 64 * 2048;
  int wpb = w * 32 * PW;

  bfrag qf[2][2];
#pragma unroll
  for (int mi = 0; mi < 2; ++mi) {
    int l = qt * 128 + w * 32 + mi * 16 + m16;
#pragma unroll
    for (int ki = 0; ki < 2; ++ki)
      qf[mi][ki] = *(const bfrag*)(qkv + ((size_t)(l * 4 + n)) * 2304 + h * 64 + ki * 32 + q4 * 8);
  }

  facc zf = {0.f, 0.f, 0.f, 0.f};
  facc accO[2][4];
#pragma unroll
  for (int mi = 0; mi < 2; ++mi)
#pragma unroll
    for (int di = 0; di < 4; ++di) accO[mi][di] = zf;
  float lrow[2][4];
#pragma unroll
  for (int mi = 0; mi < 2; ++mi)
#pragma unroll
    for (int r = 0; r < 4; ++r) lrow[mi][r] = 0.f;

  const float cs = 0.125f * 1.44269504088896f;
  int ksw = m16 & 7;

#pragma unroll
  for (int i = 0; i < 4; ++i) {
    int F = i * 256 + tid;
    int r = F >> 3, ck = (F & 7) ^ (r & 7);
    gl2lds16(qkv + ((size_t)(r * 4 + n)) * 2304 + 768 + h * 64 + ck * 8, &Kl[F * 8]);
    int d = F >> 4, cv = (F & 15) ^ (d & 7);
    gl2lds16(vtb + d * 2048 + cv * 8, &Vtl[F * 8]);
  }
  __syncthreads();

  for (int kt = 0; kt < 16; ++kt) {
    facc S[2][8];
#pragma unroll
    for (int mi = 0; mi < 2; ++mi)
#pragma unroll
      for (int ni = 0; ni < 8; ++ni) S[mi][ni] = zf;
#pragma unroll
    for (int ni = 0; ni < 8; ++ni)
#pragma unroll
      for (int ki = 0; ki < 2; ++ki) {
        bfrag bk = *(const bfrag*)&Kl[(ni * 16 + m16) * 64 + (((ki * 4 + q4) ^ ksw) << 3)];
#pragma unroll
        for (int mi = 0; mi < 2; ++mi)
          S[mi][ni] = mfma16(qf[mi][ki], bk, S[mi][ni]);
      }
    __syncthreads();   // B: K reads done (also drains V(t) staging)

    if (kt < 15) {
      int kv0 = (kt + 1) * 128;
#pragma unroll
      for (int i = 0; i < 4; ++i) {
        int F = i * 256 + tid;
        int r = F >> 3, ck = (F & 7) ^ (r & 7);
        gl2lds16(qkv + ((size_t)((kv0 + r) * 4 + n)) * 2304 + 768 + h * 64 + ck * 8, &Kl[F * 8]);
      }
    }

#pragma unroll
    for (int si = 0; si < 4; ++si) {
#pragma unroll
      for (int mi = 0; mi < 2; ++mi)
#pragma unroll
        for (int r = 0; r < 4; ++r) {
          int prow = mi * 16 + q4 * 4 + r;
          float p0 = __builtin_amdgcn_exp2f(S[mi][2 * si][r] * cs);
          float p1 = __builtin_amdgcn_exp2f(S[mi][2 * si + 1][r] * cs);
          lrow[mi][r] += p0 + p1;
          Pp[wpb + prow * PW + m16]      = (unsigned short)(__float_as_uint(p0) >> 16);
          Pp[wpb + prow * PW + 16 + m16] = (unsigned short)(__float_as_uint(p1) >> 16);
        }
      bfrag pa[2];
#pragma unroll
      for (int mi = 0; mi < 2; ++mi)
        pa[mi] = *(const bfrag*)&Pp[wpb + (mi * 16 + m16) * PW + q4 * 8];
#pragma unroll
      for (int di = 0; di < 4; ++di) {
        bfrag bv = *(const bfrag*)&Vtl[(di * 16 + m16) * 128 + (((si * 4 + q4) ^ ksw) << 3)];
#pragma unroll
        for (int mi = 0; mi < 2; ++mi)
          accO[mi][di] = mfma16(pa[mi], bv, accO[mi][di]);
      }
    }
    __syncthreads();   // C: Vt reads done; K(t+1) staging drained here

    if (kt < 15) {
      int kv0 = (kt + 1) * 128;
#pragma unroll
      for (int i = 0; i < 4; ++i) {
        int F = i * 256 + tid;
        int d = F >> 4, cv = (F & 15) ^ (d & 7);
        gl2lds16(vtb + d * 2048 + kv0 + cv * 8, &Vtl[F * 8]);
      }
    }
  }

#pragma unroll
  for (int mi = 0; mi < 2; ++mi)
#pragma unroll
    for (int r = 0; r < 4; ++r) {
      float ls = lrow[mi][r];
      ls += __shfl_xor(ls, 1);
      ls += __shfl_xor(ls, 2);
      ls += __shfl_xor(ls, 4);
      ls += __shfl_xor(ls, 8);
      float inv = 1.f / ls;
      int l = qt * 128 + w * 32 + mi * 16 + q4 * 4 + r;
#pragma unroll
      for (int di = 0; di < 4; ++di) {
        int col = h * 64 + di * 16 + m16;
        o[(size_t)(l * 4 + n) * 768 + col] = f2bf(accO[mi][di][r] * inv);
      }
    }
}

// --------------------------- launcher ---------------------------------------
extern "C" void kernel_launch(void* const* d_in, const int* in_sizes, int n_in,
                              void* d_out, int out_size, void* d_ws, size_t ws_size,
                              hipStream_t stream) {
  (void)in_sizes; (void)n_in; (void)out_size; (void)ws_size;
  const float* x      = (const float*)d_in[0];
  const float* ln1_w  = (const float*)d_in[1];
  const float* ln1_b  = (const float*)d_in[2];
  const float* w_qkv  = (const float*)d_in[3];
  const float* b_qkv  = (const float*)d_in[4];
  const float* w_out  = (const float*)d_in[5];
  const float* b_out  = (const float*)d_in[6];
  const float* ln2_w  = (const float*)d_in[7];
  const float* ln2_b  = (const float*)d_in[8];
  const float* w_fc   = (const float*)d_in[9];
  const float* b_fc   = (const float*)d_in[10];
  const float* w_proj = (const float*)d_in[11];
  const float* b_proj = (const float*)d_in[12];

  char* ws = (char*)d_ws;
  unsigned short* qkv_bf  = (unsigned short*)(ws);
  unsigned short* o_bf    = (unsigned short*)(ws + 37748736);
  unsigned short* f_bf    = (unsigned short*)(ws);
  unsigned short* h_bf    = (unsigned short*)(ws + 50331648);
  float*          x1      = (float*)        (ws + 62914560);
  unsigned short* vt      = (unsigned short*)(ws + 62914560);  // dead before x1 written
  unsigned short* wqkv_bf = (unsigned short*)(ws + 88080384);
  unsigned short* wout_bf = (unsigned short*)(ws + 91619328);
  unsigned short* wfc_bf  = (unsigned short*)(ws + 92798976);
  unsigned short* wproj_bf= (unsigned short*)(ws + 97517568);

  cvt_all_k<<<6912, 256, 0, stream>>>(w_qkv, w_out, w_fc, w_proj,
                                      wqkv_bf, wout_bf, wfc_bf, wproj_bf);

  ln_bf16_k<<<2048, 256, 0, stream>>>(x, ln1_w, ln1_b, h_bf);
  gemm_bt<0, 192><<<dim3(64, 12), 256, 0, stream>>>(h_bf, wqkv_bf, b_qkv, nullptr, qkv_bf, 768, 2304);
  vtrans_k<<<dim3(32, 48), 256, 0, stream>>>(qkv_bf, vt);
  flash_k<<<dim3(16, 48), 256, 0, stream>>>(qkv_bf, vt, o_bf);
  gemm_bt<1, 64><<<dim3(64, 12), 256, 0, stream>>>(o_bf, wout_bf, b_out, x, x1, 768, 768);
  ln_bf16_k<<<2048, 256, 0, stream>>>(x1, ln2_w, ln2_b, h_bf);
  gemm_bt<2, 128><<<dim3(64, 24), 256, 0, stream>>>(h_bf, wfc_bf, b_fc, nullptr, f_bf, 768, 3072);
  gemm_bt<1, 64><<<dim3(64, 12), 256, 0, stream>>>(f_bf, wproj_bf, b_proj, x1, (float*)d_out, 3072, 768);
}